// Round 8
// baseline (388.975 us; speedup 1.0000x reference)
//
#include <hip/hip_runtime.h>
#include <hip/hip_bf16.h>

#define BB 8
#define NN 4096
#define FF 128
#define DD 64
#define NB (BB*NN)           // 32768 rows total
#define CHK 128              // i-chunk size for rank phase P1
#define NCH (NN/CHK)         // 32 rank chunks per batch
#define CSZ 16               // stats chunk size
#define NCC (NN/CSZ)         // 256 stats chunks per batch
#define CH 72                // channel stride in stats tables (65 used: 64 ch + Z)
#define GRID 512             // mega-kernel grid (2 blocks/CU on 256 CUs)

// workspace byte offsets
#define OFF_H     0                                     // float [NB][64]   8 MB
#define OFF_S1    (OFF_H    + (size_t)NB*DD*4)
#define OFF_S2    (OFF_S1   + (size_t)NB*4)
#define OFF_S2S   (OFF_S2   + (size_t)NB*4)
#define OFF_PK    (OFF_S2S  + (size_t)NB*4)             // int2 (perm, wneg) 256 KB
#define OFF_CT16  (OFF_PK   + (size_t)NB*8)             // double [B][256][2][72] 2.36 MB
#define OFF_CTS   (OFF_CT16 + (size_t)BB*NCC*2*CH*8)    // double [B][257][2][72] 2.37 MB
#define OFF_PRANK (OFF_CTS  + (size_t)BB*(NCC+1)*2*CH*8)  // u16 [32][B][4096]  2 MB
#define OFF_BAR   (OFF_PRANK + (size_t)NCH*BB*NN*2)     // u32 [16] barrier counters

// monotone float->u32 map (IEEE total order for non-NaN)
__device__ __forceinline__ unsigned int fkey(float f) {
  unsigned int u = __float_as_uint(f);
  return (u & 0x80000000u) ? ~u : (u | 0x80000000u);
}

// grid barrier: single-use counter per sync point, zeroed by host-side memset
__device__ __forceinline__ void gridbar(unsigned int* bar, int idx) {
  __syncthreads();
  __threadfence();                      // flush this wave's writes device-wide
  if (threadIdx.x == 0) {
    __hip_atomic_fetch_add(&bar[idx], 1u, __ATOMIC_ACQ_REL, __HIP_MEMORY_SCOPE_AGENT);
    while (__hip_atomic_load(&bar[idx], __ATOMIC_ACQUIRE, __HIP_MEMORY_SCOPE_AGENT) < GRID) {
      __builtin_amdgcn_s_sleep(2);
    }
  }
  __syncthreads();
}

// ---------------- Kernel A: h = x @ W^T ; s1 = h.a1 ; s2 = h.a2 ----------------
__global__ __launch_bounds__(256) void gat_kA(const float* __restrict__ x,
                                              const float* __restrict__ W,
                                              const float* __restrict__ a,
                                              float* __restrict__ h,
                                              float* __restrict__ s1,
                                              float* __restrict__ s2) {
  __shared__ float xs[64][FF];
  const int tid  = threadIdx.x;
  const int lane = tid & 63;
  const int wave = tid >> 6;
  const long long rowbase = (long long)blockIdx.x * 64;

  const float4* x4  = (const float4*)(x + rowbase * FF);
  float4*       xs4 = (float4*)&xs[0][0];
#pragma unroll
  for (int i = 0; i < 8; ++i) xs4[tid + i * 256] = x4[tid + i * 256];

  float4 wreg[32];
  const float4* W4 = (const float4*)(W + lane * FF);
#pragma unroll
  for (int j = 0; j < 32; ++j) wreg[j] = W4[j];
  const float a1d = a[lane];
  const float a2d = a[DD + lane];
  __syncthreads();

#pragma unroll 2
  for (int r = wave * 16; r < wave * 16 + 16; ++r) {
    const float4* xr = (const float4*)&xs[r][0];
    float4 acc = {0.f, 0.f, 0.f, 0.f};
#pragma unroll
    for (int j = 0; j < 32; ++j) {
      float4 xv = xr[j];
      acc.x += xv.x * wreg[j].x;
      acc.y += xv.y * wreg[j].y;
      acc.z += xv.z * wreg[j].z;
      acc.w += xv.w * wreg[j].w;
    }
    float hd = (acc.x + acc.y) + (acc.z + acc.w);
    const long long row = rowbase + r;
    h[row * DD + lane] = hd;

    float p1 = hd * a1d, p2 = hd * a2d;
#pragma unroll
    for (int o = 32; o; o >>= 1) { p1 += __shfl_xor(p1, o); p2 += __shfl_xor(p2, o); }
    if (lane == 0) { s1[row] = p1; s2[row] = p2; }
  }
}

// ---------------- Mega-kernel: phases P1..P5 with manual grid barriers ----------
__global__ __launch_bounds__(256, 2) void gat_mega(
    const float* __restrict__ s2, float* __restrict__ s2s,
    int2* __restrict__ pk, unsigned short* __restrict__ prank,
    double* __restrict__ CT16, double* __restrict__ CTS,
    const float* __restrict__ h, const float* __restrict__ s1,
    float* __restrict__ out, unsigned int* __restrict__ bar) {
  __shared__ float key[NN];       // 16 KB (P1 aliases first 1 KB; P5 full keys)
  __shared__ float seglast[64];
  __shared__ float red[4];
  const int bid = blockIdx.x, tid = threadIdx.x, lane = tid & 63, wv = tid >> 6;

  // ---- P1: partial ranks (blocks 0..255: c = bid&31, b = bid>>5) ----
  if (bid < NCH * BB) {
    const int c = bid & (NCH - 1), b = bid >> 5;
    const float* s2b = s2 + (size_t)b * NN;
    unsigned long long* ks = (unsigned long long*)key;   // 1 KB alias
    if (tid < CHK) {
      const int ig = c * CHK + tid;
      ks[tid] = ((unsigned long long)fkey(s2b[ig]) << 12) | (unsigned)ig;
    }
    unsigned long long kj[16];
    int rank[16];
#pragma unroll
    for (int t = 0; t < 16; ++t) {
      const int j = tid + 256 * t;
      kj[t] = ((unsigned long long)fkey(s2b[j]) << 12) | (unsigned)j;
      rank[t] = 0;
    }
    __syncthreads();
#pragma unroll 4
    for (int i = 0; i < CHK; ++i) {
      const unsigned long long ki = ks[i];
#pragma unroll
      for (int t = 0; t < 16; ++t) rank[t] += (ki < kj[t]) ? 1 : 0;
    }
    unsigned short* pr = prank + ((size_t)c * BB + b) * NN;
#pragma unroll
    for (int t = 0; t < 16; ++t) pr[tid + 256 * t] = (unsigned short)rank[t];
  }
  gridbar(bar, 0);

  // ---- P2: final rank, batch max, scatter keys + packed weights (blocks 0..127) ----
  if (bid < 16 * BB) {
    const int b = bid >> 4, jt = bid & 15;
    const int j = jt * 256 + tid;
    const float* s2b = s2 + (size_t)b * NN;

    float mx = -3.4e38f;
    for (int i = tid; i < NN; i += 256) mx = fmaxf(mx, s2b[i]);
#pragma unroll
    for (int o = 32; o; o >>= 1) mx = fmaxf(mx, __shfl_xor(mx, o));
    if (lane == 0) red[wv] = mx;
    __syncthreads();
    mx = fmaxf(fmaxf(red[0], red[1]), fmaxf(red[2], red[3]));

    int rank = 0;
#pragma unroll 8
    for (int c = 0; c < NCH; ++c) rank += prank[((size_t)c * BB + b) * NN + j];

    const float kv = s2b[j];
    const float wn = expf(0.2f * (kv - mx));   // <= 1; wpos = wn^5
    const size_t o = (size_t)b * NN + rank;
    s2s[o] = kv;
    pk[o]  = make_int2(j, __float_as_int(wn));
  }
  gridbar(bar, 1);

  // ---- P5 prelude: stage this block's batch keys into LDS (overlaps P3) ----
  const int b5 = bid >> 6;                 // 64 blocks per batch
  {
    const float4* src = (const float4*)(s2s + (size_t)b5 * NN);
    float4* dst = (float4*)key;
#pragma unroll
    for (int i = 0; i < 4; ++i) dst[tid + 256 * i] = src[tid + 256 * i];
  }

  // ---- P3: 16-element chunk partial sums (2048 wave-units = 512 blocks x 4) ----
  {
    const int u = bid * 4 + wv;            // 0..2047
    const int c = u & (NCC - 1), b = u >> 8;
    const int base = b * NN + c * CSZ;
    const int d = lane;
    double ap = 0, an = 0, zp = 0, zn = 0;
#pragma unroll
    for (int s = 0; s < CSZ; ++s) {
      const int2 p = pk[base + s];
      const float hv = h[((size_t)(b * NN + p.x)) * DD + d];
      const float wn = __int_as_float(p.y);
      const float w2 = wn * wn;
      const float wp = w2 * w2 * wn;
      an += (double)wn * hv; ap += (double)wp * hv;
      zn += wn;              zp += wp;
    }
    double* o = CT16 + ((size_t)(b * NCC + c) * 2) * CH;
    o[0 * CH + d] = an;
    o[1 * CH + d] = ap;
    if (d == 0) { o[0 * CH + 64] = zn; o[1 * CH + 64] = zp; }
  }
  gridbar(bar, 2);          // syncthreads inside also publishes key[] block-wide

  if (tid < 64) seglast[tid] = key[tid * 64 + 63];

  // ---- P4: exclusive scan CT16 -> CTS (blocks 0..15; others proceed to barrier) ----
  if (bid < 2 * BB) {
    const int b = bid >> 1, fam = bid & 1;
    if (tid <= 64) {
      const int ch = tid;
      double off = 0;
#pragma unroll 16
      for (int c = 0; c < NCC; ++c) {
        CTS[(((size_t)b * (NCC + 1) + c) * 2 + fam) * CH + ch] = off;
        off += CT16[(((size_t)b * NCC + c) * 2 + fam) * CH + ch];
      }
      CTS[(((size_t)b * (NCC + 1) + NCC) * 2 + fam) * CH + ch] = off;
    }
  }
  gridbar(bar, 3);          // seglast also visible after this

  // ---- P5: ballot search + masked-unroll refine + combine + ELU ----
  {
    const int bNN = b5 * NN;
    const float c1 = key[NN - 1];
    const double* base0 = CTS + ((size_t)b5 * (NCC + 1)) * 2 * CH;
    const double* tt = base0 + (size_t)NCC * 2 * CH + CH;   // fam1 total row
    const double tot = tt[lane];
    const double Zt  = tt[64];
    const float segl = seglast[lane];
    const int g0 = bid & 63;

    for (int g = 0; g < 4; ++g) {
      const int group = g0 * 4 + g;       // 0..255
#pragma unroll
      for (int r = 0; r < 4; ++r) {
        const int rowl = group * 16 + wv * 4 + r;
        const float s1i = s1[bNN + rowl];
        const float t = -s1i;

        // 64-ary ballot search: k = #{j : key[j] <= t}
        unsigned long long m1 = __ballot(segl <= t);
        int seg = __popcll(m1); if (seg > 63) seg = 63;
        const float v2 = key[seg * 64 + lane];
        const int k = seg * 64 + __popcll(__ballot(v2 <= t));
        const int c16 = k >> 4, cnt = k & 15;   // refine count in [0,15]

        const double* r0 = base0 + (size_t)c16 * 2 * CH;
        const double* r1 = r0 + CH;
        double pre  = r0[lane];
        double p1v  = r1[lane];
        double Zpre = r0[64];
        double Z1   = r1[64];

        const int j0 = c16 << 4;
#pragma unroll
        for (int jj = 0; jj < 15; ++jj) {
          int jn = j0 + jj; jn = jn < NN ? jn : NN - 1;   // clamp (mask=0 there)
          const int2 p = pk[bNN + jn];
          const float hv = h[((size_t)(bNN + p.x)) * DD + lane];
          const float msk = (jj < cnt) ? 1.0f : 0.0f;
          const float wn = __int_as_float(p.y) * msk;
          const float w2 = wn * wn;
          const float wp = w2 * w2 * wn * msk;            // wn^5 (masked)
          pre += (double)wn * hv; p1v += (double)wp * hv;
          Zpre += wn;             Z1  += wp;
        }

        const float suf_d = (float)(tot - p1v);
        const float Zsuf  = (float)(Zt - Z1);
        const float z = s1i + c1;
        const float m = z >= 0.f ? z : 0.2f * z;
        const float A  = expf(z - m);
        const float Bn = expf(0.2f * z - m);
        const float num = A * suf_d + Bn * (float)pre;
        const float Z   = A * Zsuf  + Bn * (float)Zpre;
        const float hp  = num / Z;
        out[((size_t)(bNN + rowl)) * DD + lane] = hp > 0.f ? hp : expm1f(hp);
      }
    }
  }
}

extern "C" void kernel_launch(void* const* d_in, const int* in_sizes, int n_in,
                              void* d_out, int out_size, void* d_ws, size_t ws_size,
                              hipStream_t stream) {
  const float* x = (const float*)d_in[0];
  const float* W = (const float*)d_in[1];
  const float* a = (const float*)d_in[2];
  float* out = (float*)d_out;

  char* ws = (char*)d_ws;
  float*  h    = (float*)(ws + OFF_H);
  float*  s1   = (float*)(ws + OFF_S1);
  float*  s2   = (float*)(ws + OFF_S2);
  float*  s2s  = (float*)(ws + OFF_S2S);
  int2*   pk   = (int2*) (ws + OFF_PK);
  double* CT16 = (double*)(ws + OFF_CT16);
  double* CTS  = (double*)(ws + OFF_CTS);
  unsigned short* prank = (unsigned short*)(ws + OFF_PRANK);
  unsigned int*   bar   = (unsigned int*)(ws + OFF_BAR);

  hipMemsetAsync(bar, 0, 64, stream);
  gat_kA<<<NB / 64, 256, 0, stream>>>(x, W, a, h, s1, s2);
  gat_mega<<<GRID, 256, 0, stream>>>(s2, s2s, pk, prank, CT16, CTS, h, s1, out, bar);
}

// Round 9
// 344.245 us; speedup vs baseline: 1.1299x; 1.1299x over previous
//
#include <hip/hip_runtime.h>
#include <hip/hip_bf16.h>

#define BB 8
#define NN 4096
#define FF 128
#define DD 64
#define NB (BB*NN)           // 32768 rows total
#define CHK 128              // i-chunk size for rank phase P1
#define NCH (NN/CHK)         // 32 rank chunks per batch
#define CSZ 16               // stats chunk size
#define NCC (NN/CSZ)         // 256 stats chunks per batch
#define CH 72                // channel stride in stats tables (65 used: 64 ch + Z)
#define GRID 1024            // mega-kernel grid (4 blocks/CU on 256 CUs)

// workspace byte offsets
#define OFF_H     0                                     // float [NB][64]   8 MB
#define OFF_S1    (OFF_H    + (size_t)NB*DD*4)
#define OFF_S2    (OFF_S1   + (size_t)NB*4)
#define OFF_S2S   (OFF_S2   + (size_t)NB*4)
#define OFF_PK    (OFF_S2S  + (size_t)NB*4)             // int2 (perm, wneg) 256 KB
#define OFF_CT16  (OFF_PK   + (size_t)NB*8)             // double [B][256][2][72] 2.36 MB
#define OFF_CTS   (OFF_CT16 + (size_t)BB*NCC*2*CH*8)    // double [B][257][2][72] 2.37 MB
#define OFF_PRANK (OFF_CTS  + (size_t)BB*(NCC+1)*2*CH*8)  // u16 [32][B][4096]  2 MB
#define OFF_BAR   (OFF_PRANK + (size_t)NCH*BB*NN*2)     // u32 [16] barrier counters

// monotone float->u32 map (IEEE total order for non-NaN)
__device__ __forceinline__ unsigned int fkey(float f) {
  unsigned int u = __float_as_uint(f);
  return (u & 0x80000000u) ? ~u : (u | 0x80000000u);
}

// grid barrier: ONE release fence + relaxed add, RELAXED spin (no per-iteration
// buffer_inv!), ONE acquire fence on exit. Counter single-use per launch.
__device__ __forceinline__ void gridbar(unsigned int* bar, int idx) {
  __syncthreads();   // compiler emits s_waitcnt vmcnt(0) before s_barrier: all
                     // waves' stores are past the CU when thread 0 proceeds
  if (threadIdx.x == 0) {
    __builtin_amdgcn_fence(__ATOMIC_RELEASE, "agent");   // flush dirty L2 once
    __hip_atomic_fetch_add(&bar[idx], 1u, __ATOMIC_RELAXED, __HIP_MEMORY_SCOPE_AGENT);
    while (__hip_atomic_load(&bar[idx], __ATOMIC_RELAXED, __HIP_MEMORY_SCOPE_AGENT) < GRID) {
      __builtin_amdgcn_s_sleep(8);
    }
    __builtin_amdgcn_fence(__ATOMIC_ACQUIRE, "agent");   // invalidate once
  }
  __syncthreads();
}

// ---------------- Kernel A: h = x @ W^T ; s1 = h.a1 ; s2 = h.a2 ----------------
__global__ __launch_bounds__(256) void gat_kA(const float* __restrict__ x,
                                              const float* __restrict__ W,
                                              const float* __restrict__ a,
                                              float* __restrict__ h,
                                              float* __restrict__ s1,
                                              float* __restrict__ s2) {
  __shared__ float xs[64][FF];
  const int tid  = threadIdx.x;
  const int lane = tid & 63;
  const int wave = tid >> 6;
  const long long rowbase = (long long)blockIdx.x * 64;

  const float4* x4  = (const float4*)(x + rowbase * FF);
  float4*       xs4 = (float4*)&xs[0][0];
#pragma unroll
  for (int i = 0; i < 8; ++i) xs4[tid + i * 256] = x4[tid + i * 256];

  float4 wreg[32];
  const float4* W4 = (const float4*)(W + lane * FF);
#pragma unroll
  for (int j = 0; j < 32; ++j) wreg[j] = W4[j];
  const float a1d = a[lane];
  const float a2d = a[DD + lane];
  __syncthreads();

#pragma unroll 2
  for (int r = wave * 16; r < wave * 16 + 16; ++r) {
    const float4* xr = (const float4*)&xs[r][0];
    float4 acc = {0.f, 0.f, 0.f, 0.f};
#pragma unroll
    for (int j = 0; j < 32; ++j) {
      float4 xv = xr[j];
      acc.x += xv.x * wreg[j].x;
      acc.y += xv.y * wreg[j].y;
      acc.z += xv.z * wreg[j].z;
      acc.w += xv.w * wreg[j].w;
    }
    float hd = (acc.x + acc.y) + (acc.z + acc.w);
    const long long row = rowbase + r;
    h[row * DD + lane] = hd;

    float p1 = hd * a1d, p2 = hd * a2d;
#pragma unroll
    for (int o = 32; o; o >>= 1) { p1 += __shfl_xor(p1, o); p2 += __shfl_xor(p2, o); }
    if (lane == 0) { s1[row] = p1; s2[row] = p2; }
  }
}

// ---------------- Mega-kernel: phases P1..P5 with manual grid barriers ----------
__global__ __launch_bounds__(256, 4) void gat_mega(
    const float* __restrict__ s2, float* __restrict__ s2s,
    int2* __restrict__ pk, unsigned short* __restrict__ prank,
    double* __restrict__ CT16, double* __restrict__ CTS,
    const float* __restrict__ h, const float* __restrict__ s1,
    float* __restrict__ out, unsigned int* __restrict__ bar) {
  __shared__ float key[NN];       // 16 KB (P1 aliases first 1 KB; P5 full keys)
  __shared__ float seglast[64];
  __shared__ float red[4];
  const int bid = blockIdx.x, tid = threadIdx.x, lane = tid & 63, wv = tid >> 6;

  // ---- P1: partial ranks. 1024 blocks: b=bid&7, c=(bid>>3)&31, jt=bid>>8 ----
  {
    const int b = bid & 7, c = (bid >> 3) & 31, jt = bid >> 8;
    const float* s2b = s2 + (size_t)b * NN;
    unsigned long long* ks = (unsigned long long*)key;   // 1 KB alias
    if (tid < CHK) {
      const int ig = c * CHK + tid;
      ks[tid] = ((unsigned long long)fkey(s2b[ig]) << 12) | (unsigned)ig;
    }
    unsigned long long kj[4];
    int rank[4];
#pragma unroll
    for (int t = 0; t < 4; ++t) {
      const int j = jt * 1024 + tid + 256 * t;
      kj[t] = ((unsigned long long)fkey(s2b[j]) << 12) | (unsigned)j;
      rank[t] = 0;
    }
    __syncthreads();
#pragma unroll 8
    for (int i = 0; i < CHK; ++i) {
      const unsigned long long ki = ks[i];
#pragma unroll
      for (int t = 0; t < 4; ++t) rank[t] += (ki < kj[t]) ? 1 : 0;
    }
    unsigned short* pr = prank + ((size_t)c * BB + b) * NN;
#pragma unroll
    for (int t = 0; t < 4; ++t) pr[jt * 1024 + tid + 256 * t] = (unsigned short)rank[t];
  }
  gridbar(bar, 0);

  // ---- P2: final rank, batch max, scatter keys + packed weights (blocks 0..127) ----
  if (bid < 16 * BB) {
    const int b = bid >> 4, jt = bid & 15;
    const int j = jt * 256 + tid;
    const float* s2b = s2 + (size_t)b * NN;

    float mx = -3.4e38f;
    for (int i = tid; i < NN; i += 256) mx = fmaxf(mx, s2b[i]);
#pragma unroll
    for (int o = 32; o; o >>= 1) mx = fmaxf(mx, __shfl_xor(mx, o));
    if (lane == 0) red[wv] = mx;
    __syncthreads();
    mx = fmaxf(fmaxf(red[0], red[1]), fmaxf(red[2], red[3]));

    int rank = 0;
#pragma unroll 8
    for (int c = 0; c < NCH; ++c) rank += prank[((size_t)c * BB + b) * NN + j];

    const float kv = s2b[j];
    const float wn = expf(0.2f * (kv - mx));   // <= 1; wpos = wn^5
    const size_t o = (size_t)b * NN + rank;
    s2s[o] = kv;
    pk[o]  = make_int2(j, __float_as_int(wn));
  }
  gridbar(bar, 1);

  // ---- P5 prelude: stage this block's batch keys into LDS (overlaps P3) ----
  const int b5 = bid >> 7;                 // 128 blocks per batch
  {
    const float4* src = (const float4*)(s2s + (size_t)b5 * NN);
    float4* dst = (float4*)key;
#pragma unroll
    for (int i = 0; i < 4; ++i) dst[tid + 256 * i] = src[tid + 256 * i];
  }

  // ---- P3: 16-element chunk partial sums (2048 units = 1024 blocks x waves 0,1) ----
  if (wv < 2) {
    const int u = bid * 2 + wv;            // 0..2047
    const int c = u & (NCC - 1), b = u >> 8;
    const int base = b * NN + c * CSZ;
    const int d = lane;
    double ap = 0, an = 0, zp = 0, zn = 0;
#pragma unroll
    for (int s = 0; s < CSZ; ++s) {
      const int2 p = pk[base + s];
      const float hv = h[((size_t)(b * NN + p.x)) * DD + d];
      const float wn = __int_as_float(p.y);
      const float w2 = wn * wn;
      const float wp = w2 * w2 * wn;
      an += (double)wn * hv; ap += (double)wp * hv;
      zn += wn;              zp += wp;
    }
    double* o = CT16 + ((size_t)(b * NCC + c) * 2) * CH;
    o[0 * CH + d] = an;
    o[1 * CH + d] = ap;
    if (d == 0) { o[0 * CH + 64] = zn; o[1 * CH + 64] = zp; }
  }
  gridbar(bar, 2);          // internal syncthreads also publishes key[] block-wide

  if (tid < 64) seglast[tid] = key[tid * 64 + 63];

  // ---- P4: exclusive scan CT16 -> CTS (blocks 0..15; others idle to barrier) ----
  if (bid < 2 * BB) {
    const int b = bid >> 1, fam = bid & 1;
    if (tid <= 64) {
      const int ch = tid;
      double off = 0;
#pragma unroll 16
      for (int c = 0; c < NCC; ++c) {
        CTS[(((size_t)b * (NCC + 1) + c) * 2 + fam) * CH + ch] = off;
        off += CT16[(((size_t)b * NCC + c) * 2 + fam) * CH + ch];
      }
      CTS[(((size_t)b * (NCC + 1) + NCC) * 2 + fam) * CH + ch] = off;
    }
  }
  gridbar(bar, 3);          // seglast also visible after this

  // ---- P5: ballot search + masked-unroll refine + combine + ELU (32 rows/block) ----
  {
    const int bNN = b5 * NN;
    const float c1 = key[NN - 1];
    const double* base0 = CTS + ((size_t)b5 * (NCC + 1)) * 2 * CH;
    const double* tt = base0 + (size_t)NCC * 2 * CH + CH;   // fam1 total row
    const double tot = tt[lane];
    const double Zt  = tt[64];
    const float segl = seglast[lane];

    for (int g = 0; g < 2; ++g) {
      const int group = (bid & 127) * 2 + g;   // 0..255
#pragma unroll
      for (int r = 0; r < 4; ++r) {
        const int rowl = group * 16 + wv * 4 + r;
        const float s1i = s1[bNN + rowl];
        const float t = -s1i;

        // 64-ary ballot search: k = #{j : key[j] <= t}
        unsigned long long m1 = __ballot(segl <= t);
        int seg = __popcll(m1); if (seg > 63) seg = 63;
        const float v2 = key[seg * 64 + lane];
        const int k = seg * 64 + __popcll(__ballot(v2 <= t));
        const int c16 = k >> 4, cnt = k & 15;   // refine count in [0,15]

        const double* r0 = base0 + (size_t)c16 * 2 * CH;
        const double* r1 = r0 + CH;
        double pre  = r0[lane];
        double p1v  = r1[lane];
        double Zpre = r0[64];
        double Z1   = r1[64];

        const int j0 = c16 << 4;
#pragma unroll
        for (int jj = 0; jj < 15; ++jj) {
          int jn = j0 + jj; jn = jn < NN ? jn : NN - 1;   // clamp (mask=0 there)
          const int2 p = pk[bNN + jn];
          const float hv = h[((size_t)(bNN + p.x)) * DD + lane];
          const float msk = (jj < cnt) ? 1.0f : 0.0f;
          const float wn = __int_as_float(p.y) * msk;
          const float w2 = wn * wn;
          const float wp = w2 * w2 * wn * msk;            // wn^5 (masked)
          pre += (double)wn * hv; p1v += (double)wp * hv;
          Zpre += wn;             Z1  += wp;
        }

        const float suf_d = (float)(tot - p1v);
        const float Zsuf  = (float)(Zt - Z1);
        const float z = s1i + c1;
        const float m = z >= 0.f ? z : 0.2f * z;
        const float A  = expf(z - m);
        const float Bn = expf(0.2f * z - m);
        const float num = A * suf_d + Bn * (float)pre;
        const float Z   = A * Zsuf  + Bn * (float)Zpre;
        const float hp  = num / Z;
        out[((size_t)(bNN + rowl)) * DD + lane] = hp > 0.f ? hp : expm1f(hp);
      }
    }
  }
}

extern "C" void kernel_launch(void* const* d_in, const int* in_sizes, int n_in,
                              void* d_out, int out_size, void* d_ws, size_t ws_size,
                              hipStream_t stream) {
  const float* x = (const float*)d_in[0];
  const float* W = (const float*)d_in[1];
  const float* a = (const float*)d_in[2];
  float* out = (float*)d_out;

  char* ws = (char*)d_ws;
  float*  h    = (float*)(ws + OFF_H);
  float*  s1   = (float*)(ws + OFF_S1);
  float*  s2   = (float*)(ws + OFF_S2);
  float*  s2s  = (float*)(ws + OFF_S2S);
  int2*   pk   = (int2*) (ws + OFF_PK);
  double* CT16 = (double*)(ws + OFF_CT16);
  double* CTS  = (double*)(ws + OFF_CTS);
  unsigned short* prank = (unsigned short*)(ws + OFF_PRANK);
  unsigned int*   bar   = (unsigned int*)(ws + OFF_BAR);

  hipMemsetAsync(bar, 0, 64, stream);
  gat_kA<<<NB / 64, 256, 0, stream>>>(x, W, a, h, s1, s2);
  gat_mega<<<GRID, 256, 0, stream>>>(s2, s2s, pk, prank, CT16, CTS, h, s1, out, bar);
}

// Round 10
// 81.734 us; speedup vs baseline: 4.7590x; 4.2118x over previous
//
#include <hip/hip_runtime.h>
#include <hip/hip_bf16.h>

#define BB 8
#define NN 4096
#define FF 128
#define DD 64
#define NB (BB*NN)           // 32768 rows total
#define CHK 128              // i-chunk size for rank kernel B1
#define NCH (NN/CHK)         // 32 rank chunks per batch
#define CSZ 16               // stats chunk size
#define NC16 (NN/CSZ)        // 256 stats chunks per batch
#define CH 72                // channel stride in stats tables (65 used: 64 ch + Z)

// workspace byte offsets
#define OFF_H     0                                     // float [NB][64]   8 MB
#define OFF_S1    (OFF_H    + (size_t)NB*DD*4)
#define OFF_S2    (OFF_S1   + (size_t)NB*4)
#define OFF_S2S   (OFF_S2   + (size_t)NB*4)
#define OFF_PK    (OFF_S2S  + (size_t)NB*4)             // int2 (perm, wneg) 256 KB
#define OFF_CT16  (OFF_PK   + (size_t)NB*8)             // double [B][256][2][72] 2.36 MB
#define OFF_CTS   (OFF_CT16 + (size_t)BB*NC16*2*CH*8)   // double [B][257][2][72] 2.37 MB
#define OFF_PRANK (OFF_CTS  + (size_t)BB*(NC16+1)*2*CH*8) // u16 [32][B][4096]  2 MB

// monotone float->u32 map (IEEE total order for non-NaN)
__device__ __forceinline__ unsigned int fkey(float f) {
  unsigned int u = __float_as_uint(f);
  return (u & 0x80000000u) ? ~u : (u | 0x80000000u);
}

// ---------------- Kernel A: h = x @ W^T ; s1 = h.a1 ; s2 = h.a2 ----------------
__global__ __launch_bounds__(256) void gat_kA(const float* __restrict__ x,
                                              const float* __restrict__ W,
                                              const float* __restrict__ a,
                                              float* __restrict__ h,
                                              float* __restrict__ s1,
                                              float* __restrict__ s2) {
  __shared__ float xs[64][FF];
  const int tid  = threadIdx.x;
  const int lane = tid & 63;
  const int wave = tid >> 6;
  const long long rowbase = (long long)blockIdx.x * 64;

  const float4* x4  = (const float4*)(x + rowbase * FF);
  float4*       xs4 = (float4*)&xs[0][0];
#pragma unroll
  for (int i = 0; i < 8; ++i) xs4[tid + i * 256] = x4[tid + i * 256];

  float4 wreg[32];
  const float4* W4 = (const float4*)(W + lane * FF);
#pragma unroll
  for (int j = 0; j < 32; ++j) wreg[j] = W4[j];
  const float a1d = a[lane];
  const float a2d = a[DD + lane];
  __syncthreads();

#pragma unroll 2
  for (int r = wave * 16; r < wave * 16 + 16; ++r) {
    const float4* xr = (const float4*)&xs[r][0];
    float4 acc = {0.f, 0.f, 0.f, 0.f};
#pragma unroll
    for (int j = 0; j < 32; ++j) {
      float4 xv = xr[j];
      acc.x += xv.x * wreg[j].x;
      acc.y += xv.y * wreg[j].y;
      acc.z += xv.z * wreg[j].z;
      acc.w += xv.w * wreg[j].w;
    }
    float hd = (acc.x + acc.y) + (acc.z + acc.w);
    const long long row = rowbase + r;
    h[row * DD + lane] = hd;

    float p1 = hd * a1d, p2 = hd * a2d;
#pragma unroll
    for (int o = 32; o; o >>= 1) { p1 += __shfl_xor(p1, o); p2 += __shfl_xor(p2, o); }
    if (lane == 0) { s1[row] = p1; s2[row] = p2; }
  }
}

// ---------------- Kernel B1: partial ranks, register-blocked ----------------
__global__ __launch_bounds__(256) void gat_kB1(const float* __restrict__ s2,
                                               unsigned short* __restrict__ prank) {
  __shared__ unsigned long long ks[CHK];
  const int c = blockIdx.x, b = blockIdx.y, tid = threadIdx.x;
  const float* s2b = s2 + (size_t)b * NN;

  if (tid < CHK) {
    const int ig = c * CHK + tid;
    ks[tid] = ((unsigned long long)fkey(s2b[ig]) << 12) | (unsigned)ig;
  }

  unsigned long long kj[16];
  int rank[16];
#pragma unroll
  for (int t = 0; t < 16; ++t) {
    const int j = tid + 256 * t;
    kj[t] = ((unsigned long long)fkey(s2b[j]) << 12) | (unsigned)j;
    rank[t] = 0;
  }
  __syncthreads();

#pragma unroll 4
  for (int i = 0; i < CHK; ++i) {
    const unsigned long long ki = ks[i];
#pragma unroll
    for (int t = 0; t < 16; ++t) rank[t] += (ki < kj[t]) ? 1 : 0;
  }

  unsigned short* pr = prank + ((size_t)c * BB + b) * NN;
#pragma unroll
  for (int t = 0; t < 16; ++t) pr[tid + 256 * t] = (unsigned short)rank[t];
}

// ---------------- Kernel B2: sum partials, batch max, scatter keys + packed w ---
__global__ __launch_bounds__(256) void gat_kB2(const float* __restrict__ s2,
                                               const unsigned short* __restrict__ prank,
                                               float* __restrict__ s2s,
                                               int2* __restrict__ pk) {
  __shared__ float red[4];
  const int b = blockIdx.y, tid = threadIdx.x;
  const int j = blockIdx.x * 256 + tid;
  const float* s2b = s2 + (size_t)b * NN;

  float mx = -3.4e38f;
  for (int i = tid; i < NN; i += 256) mx = fmaxf(mx, s2b[i]);
#pragma unroll
  for (int o = 32; o; o >>= 1) mx = fmaxf(mx, __shfl_xor(mx, o));
  if ((tid & 63) == 0) red[tid >> 6] = mx;
  __syncthreads();
  mx = fmaxf(fmaxf(red[0], red[1]), fmaxf(red[2], red[3]));

  int rank = 0;
#pragma unroll 8
  for (int c = 0; c < NCH; ++c) rank += prank[((size_t)c * BB + b) * NN + j];

  const float key = s2b[j];
  const float wn = expf(0.2f * (key - mx));   // <= 1; wpos = wn^5
  const size_t o = (size_t)b * NN + rank;
  s2s[o] = key;
  pk[o]  = make_int2(j, __float_as_int(wn));
}

// ---------------- Kernel C: 16-element chunk partial sums, fp64 ----------------
__global__ __launch_bounds__(64) void gat_kC(const float* __restrict__ h,
                                             const int2* __restrict__ pk,
                                             double* __restrict__ CT16) {
  const int c = blockIdx.x, b = blockIdx.y, d = threadIdx.x;
  const int base = b * NN + c * CSZ;
  double ap = 0, an = 0, zp = 0, zn = 0;
#pragma unroll
  for (int s = 0; s < CSZ; ++s) {
    const int2 p = pk[base + s];
    const float hv = h[((size_t)(b * NN + p.x)) * DD + d];
    const float wn = __int_as_float(p.y);
    const float w2 = wn * wn;
    const float wp = w2 * w2 * wn;
    an += (double)wn * hv; ap += (double)wp * hv;
    zn += wn;              zp += wp;
  }
  double* o = CT16 + ((size_t)(b * NC16 + c) * 2) * CH;
  o[0 * CH + d] = an;   // fam0 = negative-branch (wneg)
  o[1 * CH + d] = ap;   // fam1 = positive-branch (wpos)
  if (d == 0) { o[0 * CH + 64] = zn; o[1 * CH + 64] = zp; }
}

// ---------------- Kernel D: exclusive scan CT16 -> CTS, deep unroll -------------
// grid (8 batches, 2 fams) x 128; thread = ch; 16 loads in flight per group
__global__ __launch_bounds__(128) void gat_kD(const double* __restrict__ CT16,
                                              double* __restrict__ CTS) {
  const int b = blockIdx.x, fam = blockIdx.y, ch = threadIdx.x;
  if (ch > 64) return;
  double off = 0;
#pragma unroll 16
  for (int c = 0; c < NC16; ++c) {
    CTS[(((size_t)b * (NC16 + 1) + c) * 2 + fam) * CH + ch] = off;
    off += CT16[(((size_t)b * NC16 + c) * 2 + fam) * CH + ch];
  }
  CTS[(((size_t)b * (NC16 + 1) + NC16) * 2 + fam) * CH + ch] = off;
}

// ---------------- Kernel F: ballot search + BIDIRECTIONAL masked refine + ELU ---
// grid (128 row-groups, 8 batches) x 256; 32 rows per block, 8 per wave.
// refine <= 8 elements: up from prefix(c16) if cnt<=8, else down from prefix(c16+1)
__global__ __launch_bounds__(256) void gat_kF(const float* __restrict__ s1,
                                              const float* __restrict__ s2s,
                                              const int2* __restrict__ pk,
                                              const float* __restrict__ h,
                                              const double* __restrict__ CTS,
                                              float* __restrict__ out) {
  __shared__ float key[NN];      // 16 KB
  __shared__ float seglast[64];
  const int b = blockIdx.y;
  const int tid = threadIdx.x, lane = tid & 63, wv = tid >> 6;

  const float4* src = (const float4*)(s2s + (size_t)b * NN);
  float4* dst = (float4*)key;
#pragma unroll
  for (int i = 0; i < 4; ++i) dst[tid + 256 * i] = src[tid + 256 * i];
  __syncthreads();
  if (tid < 64) seglast[tid] = key[tid * 64 + 63];
  __syncthreads();

  const int bNN = b * NN;
  const float c1 = key[NN - 1];
  const double* base0 = CTS + ((size_t)b * (NC16 + 1)) * 2 * CH;
  const double* tt = base0 + (size_t)NC16 * 2 * CH + CH;  // fam1 total row
  const double tot = tt[lane];
  const double Zt  = tt[64];
  const float segl = seglast[lane];

  const int row0 = blockIdx.x * 32 + wv * 8;
  float s1v[8];
#pragma unroll
  for (int r = 0; r < 8; ++r) s1v[r] = s1[bNN + row0 + r];

#pragma unroll 2
  for (int r = 0; r < 8; ++r) {
    const int rowl = row0 + r;
    const float s1i = s1v[r];
    const float t = -s1i;

    // 64-ary ballot search: k = #{j : key[j] <= t}
    unsigned long long m1 = __ballot(segl <= t);
    int seg = __popcll(m1); if (seg > 63) seg = 63;
    const float v2 = key[seg * 64 + lane];
    const int k = seg * 64 + __popcll(__ballot(v2 <= t));
    const int c16 = k >> 4, cnt = k & 15;

    // bidirectional refine selection (<= 8 elements either way)
    const bool up   = (cnt <= 8);
    const int  cb   = up ? c16 : c16 + 1;   // prefix row to start from (<= NC16)
    const int  nref = up ? cnt : 16 - cnt;  // number of refine elements
    const int  j0   = up ? (c16 << 4) : k;  // first refine index
    const float sgn = up ? 1.0f : -1.0f;

    const double* r0 = base0 + (size_t)cb * 2 * CH;   // fam0 prefix row
    const double* r1 = r0 + CH;                       // fam1 prefix row
    double pre  = r0[lane];
    double p1v  = r1[lane];
    double Zpre = r0[64];
    double Z1   = r1[64];

    // masked, fully-unrolled refine: 8 independent gathers; msk in {-1,0,+1}
#pragma unroll
    for (int jj = 0; jj < 8; ++jj) {
      int jn = j0 + jj; jn = jn < NN ? jn : NN - 1;   // clamp (mask=0 there)
      const int2 p = pk[bNN + jn];
      const float hv = h[((size_t)(bNN + p.x)) * DD + lane];
      const float msk = (jj < nref) ? sgn : 0.0f;
      const float w  = __int_as_float(p.y) * msk;     // +/-wn or 0
      const float w2 = w * w;
      const float wp = w2 * w2 * w;                   // wn^5 * msk
      pre += (double)w * hv; p1v += (double)wp * hv;
      Zpre += w;             Z1  += wp;
    }

    const float suf_d = (float)(tot - p1v);
    const float Zsuf  = (float)(Zt - Z1);
    const float z = s1i + c1;
    const float m = z >= 0.f ? z : 0.2f * z;
    const float A  = expf(z - m);
    const float Bn = expf(0.2f * z - m);
    const float num = A * suf_d + Bn * (float)pre;
    const float Z   = A * Zsuf  + Bn * (float)Zpre;
    const float hp  = num / Z;
    out[((size_t)(bNN + rowl)) * DD + lane] = hp > 0.f ? hp : expm1f(hp);
  }
}

extern "C" void kernel_launch(void* const* d_in, const int* in_sizes, int n_in,
                              void* d_out, int out_size, void* d_ws, size_t ws_size,
                              hipStream_t stream) {
  const float* x = (const float*)d_in[0];
  const float* W = (const float*)d_in[1];
  const float* a = (const float*)d_in[2];
  float* out = (float*)d_out;

  char* ws = (char*)d_ws;
  float*  h    = (float*)(ws + OFF_H);
  float*  s1   = (float*)(ws + OFF_S1);
  float*  s2   = (float*)(ws + OFF_S2);
  float*  s2s  = (float*)(ws + OFF_S2S);
  int2*   pk   = (int2*) (ws + OFF_PK);
  double* CT16 = (double*)(ws + OFF_CT16);
  double* CTS  = (double*)(ws + OFF_CTS);
  unsigned short* prank = (unsigned short*)(ws + OFF_PRANK);

  gat_kA<<<NB / 64, 256, 0, stream>>>(x, W, a, h, s1, s2);
  gat_kB1<<<dim3(NCH, BB), 256, 0, stream>>>(s2, prank);
  gat_kB2<<<dim3(NN / 256, BB), 256, 0, stream>>>(s2, prank, s2s, pk);
  gat_kC<<<dim3(NC16, BB), 64, 0, stream>>>(h, pk, CT16);
  gat_kD<<<dim3(BB, 2), 128, 0, stream>>>(CT16, CTS);
  gat_kF<<<dim3(NN / 32, BB), 256, 0, stream>>>(s1, s2s, pk, h, CTS, out);
}